// Round 1
// baseline (90.450 us; speedup 1.0000x reference)
//
#include <hip/hip_runtime.h>

#define S 512
#define B 128
#define H 1024

// ---------------------------------------------------------------------------
// Kernel A: u[b][h] = sum_k hidden[b][k] * W[k][h]   (u = hidden @ W)
// Grid: 256 blocks x 256 threads. Each thread computes 2 outputs (b, b+64)
// for one h, halving W L2 traffic. W loads are coalesced across threads (h
// contiguous); hidden loads are wave-uniform -> scalar loads.
// ---------------------------------------------------------------------------
__global__ __launch_bounds__(256) void calc_u(const float* __restrict__ hidden,
                                              const float* __restrict__ W,
                                              float* __restrict__ u) {
    const int h  = (blockIdx.x & 3) * 256 + threadIdx.x;  // 0..1023
    const int bb = blockIdx.x >> 2;                       // 0..63
    const int b0 = bb;
    const int b1 = bb + 64;
    const float* __restrict__ h0p = hidden + (size_t)b0 * H;
    const float* __restrict__ h1p = hidden + (size_t)b1 * H;
    float acc0 = 0.f, acc1 = 0.f;
#pragma unroll 8
    for (int k = 0; k < H; ++k) {
        float w = W[(size_t)k * H + h];
        acc0 = fmaf(h0p[k], w, acc0);
        acc1 = fmaf(h1p[k], w, acc1);
    }
    u[(size_t)b0 * H + h] = acc0;
    u[(size_t)b1 * H + h] = acc1;
}

// ---------------------------------------------------------------------------
// Kernel B: scores[b][s] = dot(enc[s][b][:], u[b][:])
// One 64-lane wave per (s,b) pair; 4 x float4 per lane = 1024 floats;
// butterfly shuffle reduce. Consecutive waves cover consecutive b -> each
// 4-wave block streams a contiguous 16 KB chunk of enc. This kernel carries
// all 268 MB of HBM traffic.
// ---------------------------------------------------------------------------
__global__ __launch_bounds__(256) void calc_scores(const float* __restrict__ enc,
                                                   const float* __restrict__ u,
                                                   float* __restrict__ scores) {
    const int wid  = threadIdx.x >> 6;
    const int lane = threadIdx.x & 63;
    const int w = blockIdx.x * 4 + wid;       // 0..65535
    const int s = w >> 7;                     // w / B
    const int b = w & (B - 1);                // w % B
    const float4* __restrict__ e4 = reinterpret_cast<const float4*>(enc + ((size_t)s * B + b) * H);
    const float4* __restrict__ u4 = reinterpret_cast<const float4*>(u + (size_t)b * H);
    float acc = 0.f;
#pragma unroll
    for (int i = 0; i < 4; ++i) {
        float4 e  = e4[i * 64 + lane];
        float4 uu = u4[i * 64 + lane];
        acc += e.x * uu.x + e.y * uu.y + e.z * uu.z + e.w * uu.w;
    }
#pragma unroll
    for (int off = 32; off >= 1; off >>= 1)
        acc += __shfl_xor(acc, off, 64);
    if (lane == 0) scores[(size_t)b * S + s] = acc;
}

// ---------------------------------------------------------------------------
// Kernel C: out[b][s] = softmax_s(scores[b][:])
// One block per b; 256 threads each own 2 of the 512 elements.
// Note: the b_attn contribution is constant across s for a given b, so it
// cancels in the softmax and is never computed.
// ---------------------------------------------------------------------------
__global__ __launch_bounds__(256) void softmax_rows(const float* __restrict__ scores,
                                                    float* __restrict__ out) {
    const int b = blockIdx.x;
    const int t = threadIdx.x;
    const int wid = t >> 6, lane = t & 63;
    const float* __restrict__ row = scores + (size_t)b * S;
    float v0 = row[t];
    float v1 = row[t + 256];

    __shared__ float sm[4], ss[4];

    float m = fmaxf(v0, v1);
#pragma unroll
    for (int off = 32; off >= 1; off >>= 1)
        m = fmaxf(m, __shfl_xor(m, off, 64));
    if (lane == 0) sm[wid] = m;
    __syncthreads();
    m = fmaxf(fmaxf(sm[0], sm[1]), fmaxf(sm[2], sm[3]));

    float e0 = __expf(v0 - m);
    float e1 = __expf(v1 - m);
    float sum = e0 + e1;
#pragma unroll
    for (int off = 32; off >= 1; off >>= 1)
        sum += __shfl_xor(sum, off, 64);
    if (lane == 0) ss[wid] = sum;
    __syncthreads();
    sum = ss[0] + ss[1] + ss[2] + ss[3];

    const float inv = 1.f / sum;
    out[(size_t)b * S + t]       = e0 * inv;
    out[(size_t)b * S + t + 256] = e1 * inv;
}

extern "C" void kernel_launch(void* const* d_in, const int* in_sizes, int n_in,
                              void* d_out, int out_size, void* d_ws, size_t ws_size,
                              hipStream_t stream) {
    const float* hidden = (const float*)d_in[0];   // [1,B,H]
    const float* enc    = (const float*)d_in[1];   // [S,B,H]
    const float* W      = (const float*)d_in[2];   // [H,H]
    // d_in[3] = b_attn: unused — constant per row, cancels in softmax.

    float* u      = (float*)d_ws;        // B*H floats   = 512 KB
    float* scores = u + (size_t)B * H;   // B*S floats   = 256 KB
    float* out    = (float*)d_out;       // [B,1,S]

    calc_u      <<<256,   256, 0, stream>>>(hidden, W, u);
    calc_scores <<<16384, 256, 0, stream>>>(enc, u, scores);
    softmax_rows<<<128,   256, 0, stream>>>(scores, out);
}

// Round 2
// 62.229 us; speedup vs baseline: 1.4535x; 1.4535x over previous
//
#include <hip/hip_runtime.h>

#define S 512
#define B 128
#define H 1024

#define KG 16          // number of k-groups (two-stage calc_u)
#define KR 64          // k per group: KG*KR == H
#define BPG 8          // b per stage-1 block
#define BG (B / BPG)   // 16 b-groups

// ---------------------------------------------------------------------------
// calc_u two-stage (u = hidden @ W), K-split for occupancy + W reuse.
// Stage 1: grid = KG*BG = 256 blocks. Block (kg,bg) computes
//   part[kg][b0..b0+7][all 1024 h] over k in [kg*KR, kg*KR+KR).
// Thread owns 4 h (float4): W loads are 1 KB/wave-instr coalesced; W is read
// once per b-group (16x = 64 MB L2 total). hidden loads are wave-uniform ->
// scalar. 2048 FMA/thread. Deterministic (fixed reduction order).
// ---------------------------------------------------------------------------
__global__ __launch_bounds__(256) void calc_u_part(const float* __restrict__ hidden,
                                                   const float* __restrict__ W,
                                                   float* __restrict__ part) {
    const int t  = threadIdx.x;            // 0..255
    const int kg = blockIdx.x & (KG - 1);  // 0..15
    const int bg = blockIdx.x >> 4;        // 0..15
    const int b0 = bg * BPG;
    const int h4 = t * 4;
    const int k0 = kg * KR;

    float4 acc[BPG];
#pragma unroll
    for (int j = 0; j < BPG; ++j) acc[j] = make_float4(0.f, 0.f, 0.f, 0.f);

#pragma unroll 4
    for (int kk = 0; kk < KR; ++kk) {
        const int k = k0 + kk;
        const float4 w = *reinterpret_cast<const float4*>(W + (size_t)k * H + h4);
#pragma unroll
        for (int j = 0; j < BPG; ++j) {
            const float hb = hidden[(size_t)(b0 + j) * H + k];  // uniform -> s_load
            acc[j].x = fmaf(hb, w.x, acc[j].x);
            acc[j].y = fmaf(hb, w.y, acc[j].y);
            acc[j].z = fmaf(hb, w.z, acc[j].z);
            acc[j].w = fmaf(hb, w.w, acc[j].w);
        }
    }
#pragma unroll
    for (int j = 0; j < BPG; ++j)
        *reinterpret_cast<float4*>(part + ((size_t)kg * B + (b0 + j)) * H + h4) = acc[j];
}

// Stage 2: u[b][h] = sum_kg part[kg][b][h]. 512 blocks x 256 threads,
// 16 coalesced strided loads per thread (8.4 MB from L2).
__global__ __launch_bounds__(256) void calc_u_reduce(const float* __restrict__ part,
                                                     float* __restrict__ u) {
    const int idx = blockIdx.x * 256 + threadIdx.x;  // b*H + h
    float s = 0.f;
#pragma unroll
    for (int kg = 0; kg < KG; ++kg)
        s += part[(size_t)kg * (B * H) + idx];
    u[idx] = s;
}

// Fallback single-stage calc_u (if workspace too small). Unroll 16 to get
// ~4 MB of loads in flight across the grid.
__global__ __launch_bounds__(256) void calc_u_fallback(const float* __restrict__ hidden,
                                                       const float* __restrict__ W,
                                                       float* __restrict__ u) {
    const int h  = (blockIdx.x & 3) * 256 + threadIdx.x;
    const int bb = blockIdx.x >> 2;
    const float* __restrict__ h0p = hidden + (size_t)bb * H;
    const float* __restrict__ h1p = hidden + (size_t)(bb + 64) * H;
    float acc0 = 0.f, acc1 = 0.f;
#pragma unroll 16
    for (int k = 0; k < H; ++k) {
        float w = W[(size_t)k * H + h];
        acc0 = fmaf(h0p[k], w, acc0);
        acc1 = fmaf(h1p[k], w, acc1);
    }
    u[(size_t)bb * H + h] = acc0;
    u[(size_t)(bb + 64) * H + h] = acc1;
}

// ---------------------------------------------------------------------------
// calc_scores: scores[b][s] = dot(enc[s][b][:], u[b][:]).
// One wave per (b, 4 s-values); u held in 16 VGPRs (read once per wave ->
// u traffic cut 4x, VMEM instrs -40%). Block's 4 waves cover b..b+3 at the
// same s -> 16 KB contiguous enc per j-iteration. Carries the 268 MB stream.
// ---------------------------------------------------------------------------
__global__ __launch_bounds__(256) void calc_scores(const float* __restrict__ enc,
                                                   const float* __restrict__ u,
                                                   float* __restrict__ scores) {
    const int wid  = threadIdx.x >> 6;
    const int lane = threadIdx.x & 63;
    const int w  = blockIdx.x * 4 + wid;  // 0..16383
    const int b  = w & (B - 1);
    const int sb = w >> 7;                // 0..127
    const float4* __restrict__ u4 = reinterpret_cast<const float4*>(u + (size_t)b * H);
    const float4 uu0 = u4[lane];
    const float4 uu1 = u4[64 + lane];
    const float4 uu2 = u4[128 + lane];
    const float4 uu3 = u4[192 + lane];
#pragma unroll
    for (int j = 0; j < 4; ++j) {
        const int s = sb + j * 128;
        const float4* __restrict__ e4 =
            reinterpret_cast<const float4*>(enc + ((size_t)s * B + b) * H);
        const float4 e0 = e4[lane];
        const float4 e1 = e4[64 + lane];
        const float4 e2 = e4[128 + lane];
        const float4 e3 = e4[192 + lane];
        float acc = e0.x * uu0.x + e0.y * uu0.y + e0.z * uu0.z + e0.w * uu0.w;
        acc = fmaf(e1.x, uu1.x, acc); acc = fmaf(e1.y, uu1.y, acc);
        acc = fmaf(e1.z, uu1.z, acc); acc = fmaf(e1.w, uu1.w, acc);
        acc = fmaf(e2.x, uu2.x, acc); acc = fmaf(e2.y, uu2.y, acc);
        acc = fmaf(e2.z, uu2.z, acc); acc = fmaf(e2.w, uu2.w, acc);
        acc = fmaf(e3.x, uu3.x, acc); acc = fmaf(e3.y, uu3.y, acc);
        acc = fmaf(e3.z, uu3.z, acc); acc = fmaf(e3.w, uu3.w, acc);
#pragma unroll
        for (int off = 32; off >= 1; off >>= 1)
            acc += __shfl_xor(acc, off, 64);
        if (lane == 0) scores[(size_t)b * S + s] = acc;
    }
}

// ---------------------------------------------------------------------------
// softmax over s per b. b_attn never computed: constant per row -> cancels.
// ---------------------------------------------------------------------------
__global__ __launch_bounds__(256) void softmax_rows(const float* __restrict__ scores,
                                                    float* __restrict__ out) {
    const int b = blockIdx.x;
    const int t = threadIdx.x;
    const int wid = t >> 6, lane = t & 63;
    const float* __restrict__ row = scores + (size_t)b * S;
    float v0 = row[t];
    float v1 = row[t + 256];

    __shared__ float sm[4], ss[4];

    float m = fmaxf(v0, v1);
#pragma unroll
    for (int off = 32; off >= 1; off >>= 1)
        m = fmaxf(m, __shfl_xor(m, off, 64));
    if (lane == 0) sm[wid] = m;
    __syncthreads();
    m = fmaxf(fmaxf(sm[0], sm[1]), fmaxf(sm[2], sm[3]));

    float e0 = __expf(v0 - m);
    float e1 = __expf(v1 - m);
    float sum = e0 + e1;
#pragma unroll
    for (int off = 32; off >= 1; off >>= 1)
        sum += __shfl_xor(sum, off, 64);
    if (lane == 0) ss[wid] = sum;
    __syncthreads();
    sum = ss[0] + ss[1] + ss[2] + ss[3];

    const float inv = 1.f / sum;
    out[(size_t)b * S + t]       = e0 * inv;
    out[(size_t)b * S + t + 256] = e1 * inv;
}

extern "C" void kernel_launch(void* const* d_in, const int* in_sizes, int n_in,
                              void* d_out, int out_size, void* d_ws, size_t ws_size,
                              hipStream_t stream) {
    const float* hidden = (const float*)d_in[0];   // [1,B,H]
    const float* enc    = (const float*)d_in[1];   // [S,B,H]
    const float* W      = (const float*)d_in[2];   // [H,H]
    // d_in[3] = b_attn: unused — constant per row, cancels in softmax.

    float* u      = (float*)d_ws;                       // B*H floats
    float* scores = u + (size_t)B * H;                  // B*S floats
    float* part   = scores + (size_t)B * S;             // KG*B*H floats
    float* out    = (float*)d_out;                      // [B,1,S]

    const size_t need = ((size_t)B * H + (size_t)B * S + (size_t)KG * B * H) * sizeof(float);
    if (ws_size >= need) {
        calc_u_part  <<<KG * BG, 256, 0, stream>>>(hidden, W, part);
        calc_u_reduce<<<(B * H) / 256, 256, 0, stream>>>(part, u);
    } else {
        calc_u_fallback<<<256, 256, 0, stream>>>(hidden, W, u);
    }
    calc_scores <<<4096, 256, 0, stream>>>(enc, u, scores);
    softmax_rows<<<128,  256, 0, stream>>>(scores, out);
}